// Round 7
// baseline (581.722 us; speedup 1.0000x reference)
//
#include <hip/hip_runtime.h>
#include <cstdint>
#include <cstddef>

// ---------------- dims ----------------
#define BATCH 2
#define MQ 12544          // B * TQ * NQ
#define ROWS_Q 6272
#define MK 4096           // B * T*H*W
#define ROWS_K 2048
#define HID 512
#define NH 4
#define HD 128
#define EMB 1024
#define DQ 896
#define FF 1024
#define OUTD 896
#define NSPLIT 4

typedef __bf16 bf16;
typedef unsigned int u32;
typedef bf16 bf16x8 __attribute__((ext_vector_type(8)));
typedef bf16 bf16x4 __attribute__((ext_vector_type(4)));
typedef float f32x4 __attribute__((ext_vector_type(4)));

enum { OP_BIAS = 0, OP_GELU = 1, OP_RES = 2 };

__device__ __forceinline__ float gelu_tanh(float x) {
    float x3 = x * x * x;
    return 0.5f * x * (1.0f + tanhf(0.7978845608028654f * (x + 0.044715f * x3)));
}

__device__ __forceinline__ void gld16(const bf16* g, bf16* l) {
    __builtin_amdgcn_global_load_lds(
        (const __attribute__((address_space(1))) unsigned int*)g,
        (__attribute__((address_space(3))) unsigned int*)l, 16, 0, 0);
}

__device__ __forceinline__ u32 pack_bf16(float a, float b) {
    union { bf16 h[2]; u32 w; } u;
    u.h[0] = (bf16)a; u.h[1] = (bf16)b;
    return u.w;
}

// ---------------------------------------------------------------------------
// bf16 MFMA GEMM, 128x128 tile (m97 structure).
// ---------------------------------------------------------------------------
template <int OP, bool WF32, bool WB16>
__global__ __launch_bounds__(256) void mgemm(
    const bf16* __restrict__ A, const bf16* __restrict__ Bt,
    const float* __restrict__ bias, const float* __restrict__ res,
    float* __restrict__ Cf, bf16* __restrict__ Cb, int M, int N, int K)
{
    __shared__ __align__(16) bf16 As[128 * 32];
    __shared__ __align__(16) bf16 Bs[128 * 32];
    const int tid  = threadIdx.x;
    const int m0   = blockIdx.y * 128;
    const int n0   = blockIdx.x * 128;
    const int wave = tid >> 6, lane = tid & 63;
    const int wm = (wave >> 1) * 64, wn = (wave & 1) * 64;

    f32x4 acc[4][4] = {};

    const int srow = tid >> 2;
    const int scol = (tid & 3) * 8;
    const bf16* Ag = A  + (size_t)(m0 + srow) * K + scol;
    const bf16* Bg = Bt + (size_t)(n0 + srow) * K + scol;
    bf16* Al = &As[tid * 8];
    bf16* Bl = &Bs[tid * 8];
    const size_t half = (size_t)64 * K;

    const int fr = lane & 15;
    const int kq = (lane >> 4) * 8;
    const bf16* pa = &As[(wm + fr) * 32 + kq];
    const bf16* pb = &Bs[(wn + fr) * 32 + kq];

    for (int k0 = 0; k0 < K; k0 += 32) {
        gld16(Ag + k0,        Al);
        gld16(Ag + k0 + half, Al + 64 * 32);
        gld16(Bg + k0,        Bl);
        gld16(Bg + k0 + half, Bl + 64 * 32);
        __syncthreads();

        bf16x8 af[4], bfr[4];
        #pragma unroll
        for (int i = 0; i < 4; ++i) af[i]  = *(const bf16x8*)(pa + i * 16 * 32);
        #pragma unroll
        for (int j = 0; j < 4; ++j) bfr[j] = *(const bf16x8*)(pb + j * 16 * 32);
        #pragma unroll
        for (int i = 0; i < 4; ++i)
            #pragma unroll
            for (int j = 0; j < 4; ++j)
                acc[i][j] = __builtin_amdgcn_mfma_f32_16x16x32_bf16(
                    af[i], bfr[j], acc[i][j], 0, 0, 0);
        __syncthreads();
    }

    const int colb = n0 + wn + (lane & 15);
    const int rowb = m0 + wm + (lane >> 4) * 4;
    #pragma unroll
    for (int i = 0; i < 4; ++i) {
        #pragma unroll
        for (int j = 0; j < 4; ++j) {
            const int c = colb + j * 16;
            const float bj = bias[c];
            #pragma unroll
            for (int r = 0; r < 4; ++r) {
                const int m = rowb + i * 16 + r;
                float v = acc[i][j][r] + bj;
                if (OP == OP_GELU) v = gelu_tanh(v);
                if (OP == OP_RES)  v += res[(size_t)m * N + c];
                if (WF32) Cf[(size_t)m * N + c] = v;
                if (WB16) Cb[(size_t)m * N + c] = (bf16)v;
            }
        }
    }
}

// ---------------------------------------------------------------------------
// bf16 MFMA GEMM, 64x128 tile, for occupancy-starved N=512 shapes.
// ---------------------------------------------------------------------------
template <int OP, bool WF32, bool WB16>
__global__ __launch_bounds__(256) void mgemm64(
    const bf16* __restrict__ A, const bf16* __restrict__ Bt,
    const float* __restrict__ bias, const float* __restrict__ res,
    float* __restrict__ Cf, bf16* __restrict__ Cb, int M, int N, int K)
{
    __shared__ __align__(16) bf16 As[64 * 32];
    __shared__ __align__(16) bf16 Bs[128 * 32];
    const int tid  = threadIdx.x;
    const int m0   = blockIdx.y * 64;
    const int n0   = blockIdx.x * 128;
    const int wave = tid >> 6, lane = tid & 63;
    const int wm = (wave >> 1) * 32, wn = (wave & 1) * 64;

    f32x4 acc[2][4] = {};

    const int srow = tid >> 2;
    const int scol = (tid & 3) * 8;
    const bf16* Ag = A  + (size_t)(m0 + srow) * K + scol;
    const bf16* Bg = Bt + (size_t)(n0 + srow) * K + scol;
    bf16* Al = &As[tid * 8];
    bf16* Bl = &Bs[tid * 8];
    const size_t half = (size_t)64 * K;

    const int fr = lane & 15;
    const int kq = (lane >> 4) * 8;
    const bf16* pa = &As[(wm + fr) * 32 + kq];
    const bf16* pb = &Bs[(wn + fr) * 32 + kq];

    for (int k0 = 0; k0 < K; k0 += 32) {
        gld16(Ag + k0,        Al);
        gld16(Bg + k0,        Bl);
        gld16(Bg + k0 + half, Bl + 64 * 32);
        __syncthreads();

        bf16x8 af[2], bfr[4];
        #pragma unroll
        for (int i = 0; i < 2; ++i) af[i]  = *(const bf16x8*)(pa + i * 16 * 32);
        #pragma unroll
        for (int j = 0; j < 4; ++j) bfr[j] = *(const bf16x8*)(pb + j * 16 * 32);
        #pragma unroll
        for (int i = 0; i < 2; ++i)
            #pragma unroll
            for (int j = 0; j < 4; ++j)
                acc[i][j] = __builtin_amdgcn_mfma_f32_16x16x32_bf16(
                    af[i], bfr[j], acc[i][j], 0, 0, 0);
        __syncthreads();
    }

    const int colb = n0 + wn + (lane & 15);
    const int rowb = m0 + wm + (lane >> 4) * 4;
    #pragma unroll
    for (int i = 0; i < 2; ++i) {
        #pragma unroll
        for (int j = 0; j < 4; ++j) {
            const int c = colb + j * 16;
            const float bj = bias[c];
            #pragma unroll
            for (int r = 0; r < 4; ++r) {
                const int m = rowb + i * 16 + r;
                float v = acc[i][j][r] + bj;
                if (OP == OP_GELU) v = gelu_tanh(v);
                if (OP == OP_RES)  v += res[(size_t)m * N + c];
                if (WF32) Cf[(size_t)m * N + c] = v;
                if (WB16) Cb[(size_t)m * N + c] = (bf16)v;
            }
        }
    }
}

// ---------------------------------------------------------------------------
// All 9 weight transposes (fp32 KxN -> bf16 NxK) in ONE launch.
// ---------------------------------------------------------------------------
struct TDesc { const float* src; bf16* dst; int K; int N; int tile0; };
struct TDescs { TDesc d[9]; };

__global__ __launch_bounds__(256) void transpose_all(TDescs td)
{
    __shared__ float t[32][33];
    const int blk = blockIdx.x;
    int i = 0;
    #pragma unroll
    for (int j = 1; j < 9; ++j) if (blk >= td.d[j].tile0) i = j;
    const float* src = td.d[i].src;
    bf16* dst = td.d[i].dst;
    const int K = td.d[i].K, N = td.d[i].N;
    const int local = blk - td.d[i].tile0;
    const int ntx = N >> 5;
    const int bx = local % ntx, by = local / ntx;
    const int x = threadIdx.x & 31, y = threadIdx.x >> 5;
    #pragma unroll
    for (int p = 0; p < 32; p += 8)
        t[y + p][x] = src[(size_t)(by * 32 + y + p) * N + bx * 32 + x];
    __syncthreads();
    #pragma unroll
    for (int p = 0; p < 32; p += 8)
        dst[(size_t)(bx * 32 + y + p) * K + by * 32 + x] = (bf16)t[x][y + p];
}

// fp32 -> bf16 elementwise
__global__ __launch_bounds__(256) void cvt_kernel(
    const float* __restrict__ in, bf16* __restrict__ out, int n4)
{
    int i = blockIdx.x * 256 + threadIdx.x;
    if (i >= n4) return;
    float4 v = ((const float4*)in)[i];
    out[4 * i + 0] = (bf16)v.x;
    out[4 * i + 1] = (bf16)v.y;
    out[4 * i + 2] = (bf16)v.z;
    out[4 * i + 3] = (bf16)v.w;
}

// kv = x @ Wm + bm  (K=4), bf16 out.
__global__ __launch_bounds__(256) void kv_kernel(
    const float* __restrict__ x, const float* __restrict__ Wm,
    const float* __restrict__ bm, bf16* __restrict__ kv)
{
    int idx = blockIdx.x * 256 + threadIdx.x;
    int r = idx >> 10, n = idx & 1023;
    float4 xv = *(const float4*)(x + (size_t)r * 4);
    float v = bm[n] + xv.x * Wm[n] + xv.y * Wm[1024 + n]
                    + xv.z * Wm[2048 + n] + xv.w * Wm[3072 + n];
    kv[idx] = (bf16)v;
}

// Fused 3D RoPE for q (from q16, scaled) and k (from kv16 cols 0..511).
__global__ __launch_bounds__(256) void rope2_kernel(
    const bf16* __restrict__ q16, const bf16* __restrict__ kv16,
    bf16* __restrict__ qbt, bf16* __restrict__ kbt)
{
    int idx = blockIdx.x * 256 + threadIdx.x;
    const bf16* in; bf16* out;
    int tok, gdiv, wdiv, istr; float sc;
    if (idx < MQ * 128) {
        in = q16; out = qbt; tok = ROWS_Q; gdiv = 196; wdiv = 14; istr = 512;
        sc = 0.08838834764831843f;
    } else {
        idx -= MQ * 128;
        if (idx >= MK * 128) return;
        in = kv16; out = kbt; tok = ROWS_K; gdiv = 64; wdiv = 8; istr = 1024;
        sc = 1.0f;
    }
    int row = idx >> 7;
    int r2 = idx & 127;
    int h = r2 >> 5;
    int j = 2 * (r2 & 31);
    int n = row % tok;
    int t = n / gdiv;
    int g = n % gdiv;
    int gh = g / wdiv;
    int gw = g % wdiv;
    float pa = (j < 22) ? (float)t : (j < 43) ? (float)gh : (float)gw;
    int j1 = j + 1;
    float pb = (j1 < 22) ? (float)t : (j1 < 43) ? (float)gh : (float)gw;
    float fra = pa * exp2f(-(float)j  * 0.20762050593045954f);
    float frb = pb * exp2f(-(float)j1 * 0.20762050593045954f);
    float ca = cosf(fra), sa = sinf(fra);
    float cb = cosf(frb), sb = sinf(frb);
    size_t ibase = (size_t)row * istr + (size_t)h * 128 + j;
    size_t obase = (size_t)row * 512 + (size_t)h * 128 + j;
    union { u32 w; bf16 e[2]; } ua, ub;
    ua.w = *(const u32*)(in + ibase);
    ub.w = *(const u32*)(in + ibase + 64);
    float x1a = (float)ua.e[0], x1b = (float)ua.e[1];
    float x2a = (float)ub.e[0], x2b = (float)ub.e[1];
    *(u32*)(out + obase)      = pack_bf16((x1a * ca - x2a * sa) * sc,
                                          (x1b * cb - x2b * sb) * sc);
    *(u32*)(out + obase + 64) = pack_bf16((x2a * ca + x1a * sa) * sc,
                                          (x2b * cb + x1b * sb) * sc);
}

// Coalesced V transpose: kv16[t][512 + h*128 + d] -> Vt[b][h][d][2048]
__global__ __launch_bounds__(256) void vt_tiled(
    const bf16* __restrict__ kv16, bf16* __restrict__ vt)
{
    __shared__ bf16 t[64][72];
    const int tt = blockIdx.x * 64;
    const int d0 = blockIdx.y * 64;
    const int bh = blockIdx.z;
    const int b = bh >> 2, h = bh & 3;
    const int rr = threadIdx.x >> 4;
    const int cc = (threadIdx.x & 15) * 4;
    #pragma unroll
    for (int p = 0; p < 4; ++p) {
        int r = rr + p * 16;
        *(bf16x4*)&t[r][cc] = *(const bf16x4*)
            (kv16 + (size_t)(b * ROWS_K + tt + r) * 1024 + 512 + h * 128 + d0 + cc);
    }
    __syncthreads();
    #pragma unroll
    for (int p = 0; p < 4; ++p) {
        int r = rr + p * 16;
        bf16x4 v;
        v[0] = t[cc + 0][r]; v[1] = t[cc + 1][r];
        v[2] = t[cc + 2][r]; v[3] = t[cc + 3][r];
        *(bf16x4*)(vt + (size_t)bh * HD * ROWS_K + (size_t)(d0 + r) * ROWS_K + tt + cc) = v;
    }
}

// LayerNorm in-place on (rows x 512) + bf16 copy.
__global__ __launch_bounds__(256) void ln_kernel(
    float* __restrict__ xb, const float* __restrict__ g,
    const float* __restrict__ be, bf16* __restrict__ out16)
{
    int wave = threadIdx.x >> 6, lane = threadIdx.x & 63;
    size_t row = (size_t)blockIdx.x * 4 + wave;
    float* xp = xb + row * 512;
    float4 a = ((const float4*)xp)[lane];
    float4 b = ((const float4*)xp)[lane + 64];
    float s  = a.x + a.y + a.z + a.w + b.x + b.y + b.z + b.w;
    float sq = a.x*a.x + a.y*a.y + a.z*a.z + a.w*a.w
             + b.x*b.x + b.y*b.y + b.z*b.z + b.w*b.w;
    #pragma unroll
    for (int off = 32; off; off >>= 1) {
        s  += __shfl_xor(s, off);
        sq += __shfl_xor(sq, off);
    }
    float mean = s * (1.0f / 512.0f);
    float var  = sq * (1.0f / 512.0f) - mean * mean;
    float rstd = rsqrtf(var + 1e-5f);
    float4 gv1 = ((const float4*)g)[lane],  gv2 = ((const float4*)g)[lane + 64];
    float4 bv1 = ((const float4*)be)[lane], bv2 = ((const float4*)be)[lane + 64];
    a.x = (a.x - mean) * rstd * gv1.x + bv1.x;
    a.y = (a.y - mean) * rstd * gv1.y + bv1.y;
    a.z = (a.z - mean) * rstd * gv1.z + bv1.z;
    a.w = (a.w - mean) * rstd * gv1.w + bv1.w;
    b.x = (b.x - mean) * rstd * gv2.x + bv2.x;
    b.y = (b.y - mean) * rstd * gv2.y + bv2.y;
    b.z = (b.z - mean) * rstd * gv2.z + bv2.z;
    b.w = (b.w - mean) * rstd * gv2.w + bv2.w;
    ((float4*)xp)[lane]      = a;
    ((float4*)xp)[lane + 64] = b;
    bf16* op = out16 + row * 512;
    *(u32*)(op + lane * 4)       = pack_bf16(a.x, a.y);
    *(u32*)(op + lane * 4 + 2)   = pack_bf16(a.z, a.w);
    *(u32*)(op + 256 + lane * 4)     = pack_bf16(b.x, b.y);
    *(u32*)(op + 256 + lane * 4 + 2) = pack_bf16(b.z, b.w);
}

// ---------------------------------------------------------------------------
// MFMA flash attention, 4-way split-KV. blockIdx.y = split (8 K-tiles each).
// Writes normalized partial O (bf16, standard layout) + (m,l) per q row.
// ---------------------------------------------------------------------------
__global__ __launch_bounds__(256, 2) void mattn_kernel(
    const bf16* __restrict__ qs, const bf16* __restrict__ ks,
    const bf16* __restrict__ vt,
    bf16* __restrict__ o0, bf16* __restrict__ o1,
    bf16* __restrict__ o2, bf16* __restrict__ o3,
    float2* __restrict__ mlbuf)
{
    __shared__ __align__(16) char smem[35840];
    bf16* Ksh = (bf16*)smem;            // [64][136]
    bf16* Vsh = (bf16*)(smem + 17408);  // [128][72]

    const int tid = threadIdx.x;
    const int wave = tid >> 6, lane = tid & 63;
    const int quad = lane >> 4, c = lane & 15;
    const int bid = blockIdx.x;
    const int split = blockIdx.y;
    const int qt = bid % 49;
    const int h  = (bid / 49) & 3;
    const int b  = bid / 196;

    const int q0 = qt * 128 + wave * 32;
    const bf16* qg = qs + (size_t)(b * ROWS_Q + q0) * HID + h * HD;
    const bf16* kg = ks + (size_t)(b * ROWS_K) * HID + h * HD;
    const bf16* vg = vt + (size_t)(b * NH + h) * HD * ROWS_K;
    bf16* outp = (split == 0) ? o0 : (split == 1) ? o1 : (split == 2) ? o2 : o3;

    bf16x8 qf[2][4];
    #pragma unroll
    for (int n = 0; n < 2; ++n)
        #pragma unroll
        for (int s = 0; s < 4; ++s)
            qf[n][s] = *(const bf16x8*)(qg + (size_t)(n * 16 + c) * HID + s * 32 + quad * 8);

    f32x4 o[8][2] = {};
    float m_i[2] = {-1e30f, -1e30f}, l_i[2] = {0.0f, 0.0f};

    const int st_t = tid >> 2;
    const int st_d = (tid & 3) * 32;
    const int sv_d = tid >> 1;
    const int sv_t = (tid & 1) * 32;

    const int kt0 = split * 8;
    for (int kt = kt0; kt < kt0 + 8; ++kt) {
        __syncthreads();
        {
            const bf16* src = kg + (size_t)(kt * 64 + st_t) * HID + st_d;
            bf16* dst = Ksh + st_t * 136 + st_d;
            #pragma unroll
            for (int i = 0; i < 4; ++i)
                *(bf16x8*)(dst + i * 8) = *(const bf16x8*)(src + i * 8);
        }
        {
            const bf16* src = vg + (size_t)sv_d * ROWS_K + kt * 64 + sv_t;
            bf16* dst = Vsh + sv_d * 72 + sv_t;
            #pragma unroll
            for (int i = 0; i < 4; ++i)
                *(bf16x8*)(dst + i * 8) = *(const bf16x8*)(src + i * 8);
        }
        __syncthreads();

        f32x4 s[4][2] = {};
        #pragma unroll
        for (int ksi = 0; ksi < 4; ++ksi) {
            bf16x8 kf[4];
            #pragma unroll
            for (int mi = 0; mi < 4; ++mi)
                kf[mi] = *(const bf16x8*)(Ksh + (mi * 16 + c) * 136 + ksi * 32 + quad * 8);
            #pragma unroll
            for (int mi = 0; mi < 4; ++mi)
                #pragma unroll
                for (int n = 0; n < 2; ++n)
                    s[mi][n] = __builtin_amdgcn_mfma_f32_16x16x32_bf16(
                        kf[mi], qf[n][ksi], s[mi][n], 0, 0, 0);
        }

        float alpha[2];
        #pragma unroll
        for (int n = 0; n < 2; ++n) {
            float mx = -1e30f;
            #pragma unroll
            for (int mi = 0; mi < 4; ++mi)
                #pragma unroll
                for (int r = 0; r < 4; ++r) mx = fmaxf(mx, s[mi][n][r]);
            mx = fmaxf(mx, __shfl_xor(mx, 16));
            mx = fmaxf(mx, __shfl_xor(mx, 32));
            float mn = fmaxf(m_i[n], mx);
            alpha[n] = __expf(m_i[n] - mn);
            m_i[n] = mn;
            float sm = 0.0f;
            #pragma unroll
            for (int mi = 0; mi < 4; ++mi)
                #pragma unroll
                for (int r = 0; r < 4; ++r) {
                    float p = __expf(s[mi][n][r] - mn);
                    s[mi][n][r] = p;
                    sm += p;
                }
            sm += __shfl_xor(sm, 16);
            sm += __shfl_xor(sm, 32);
            l_i[n] = l_i[n] * alpha[n] + sm;
            #pragma unroll
            for (int md = 0; md < 8; ++md) {
                o[md][n][0] *= alpha[n]; o[md][n][1] *= alpha[n];
                o[md][n][2] *= alpha[n]; o[md][n][3] *= alpha[n];
            }
        }

        u32 pk[4][2][2];
        #pragma unroll
        for (int mi = 0; mi < 4; ++mi)
            #pragma unroll
            for (int n = 0; n < 2; ++n) {
                pk[mi][n][0] = pack_bf16(s[mi][n][0], s[mi][n][1]);
                pk[mi][n][1] = pack_bf16(s[mi][n][2], s[mi][n][3]);
            }
        bf16x8 pf[2][2];
        #pragma unroll
        for (int kst = 0; kst < 2; ++kst)
            #pragma unroll
            for (int n = 0; n < 2; ++n) {
                union { bf16x8 v8; u32 d[4]; } u;
                #pragma unroll
                for (int dw = 0; dw < 4; ++dw) {
                    int srcl = ((quad & 1) * 2 + (dw >> 1)) * 16 + c;
                    u32 lo = (u32)__shfl((int)pk[2 * kst][n][dw & 1], srcl);
                    u32 hi = (u32)__shfl((int)pk[2 * kst + 1][n][dw & 1], srcl);
                    u.d[dw] = (quad >= 2) ? hi : lo;
                }
                pf[kst][n] = u.v8;
            }

        #pragma unroll
        for (int kst = 0; kst < 2; ++kst)
            #pragma unroll
            for (int md = 0; md < 8; ++md) {
                bf16x8 vf = *(const bf16x8*)(Vsh + (md * 16 + c) * 72 + kst * 32 + quad * 8);
                #pragma unroll
                for (int n = 0; n < 2; ++n)
                    o[md][n] = __builtin_amdgcn_mfma_f32_16x16x32_bf16(
                        vf, pf[kst][n], o[md][n], 0, 0, 0);
            }
    }

    // ---- epilogue: normalize, write partial O + (m,l) ----
    __syncthreads();
    bf16* Osh = (bf16*)smem + wave * (32 * 136);
    float inv[2] = {1.0f / l_i[0], 1.0f / l_i[1]};
    #pragma unroll
    for (int md = 0; md < 8; ++md)
        #pragma unroll
        for (int n = 0; n < 2; ++n)
            #pragma unroll
            for (int hh = 0; hh < 2; ++hh) {
                u32 w = pack_bf16(o[md][n][2 * hh] * inv[n], o[md][n][2 * hh + 1] * inv[n]);
                int d = md * 16 + quad * 4 + 2 * hh;
                int qq = n * 16 + c;
                *(u32*)(Osh + qq * 136 + d) = w;
            }
    if (quad == 0) {
        #pragma unroll
        for (int n = 0; n < 2; ++n) {
            int q = q0 + n * 16 + c;
            mlbuf[((size_t)(split * BATCH + b) * NH + h) * ROWS_Q + q] =
                make_float2(m_i[n], l_i[n]);
        }
    }
    __syncthreads();
    bf16* og = outp + (size_t)(b * ROWS_Q + q0) * HID + h * HD;
    #pragma unroll
    for (int i = 0; i < 8; ++i) {
        int idx = i * 64 + lane;
        int qq = idx >> 4;
        int ch = idx & 15;
        bf16x8 vv = *(const bf16x8*)(Osh + qq * 136 + ch * 8);
        *(bf16x8*)(og + (size_t)qq * HID + ch * 8) = vv;
    }
}

// Combine 4 normalized partials. outb MAY alias o0 (same per-thread index:
// read-before-write) — so o0/outb are NOT __restrict__.
__global__ __launch_bounds__(256) void combine_kernel(
    const bf16* o0, const bf16* __restrict__ o1,
    const bf16* __restrict__ o2, const bf16* __restrict__ o3,
    const float2* __restrict__ ml, bf16* outb)
{
    int gid = blockIdx.x * 256 + threadIdx.x;   // MQ*64 groups of 8
    if (gid >= MQ * 64) return;
    int row = gid >> 6;
    int g = gid & 63;
    int h = g >> 4;
    int b = row / ROWS_Q;
    int q = row - b * ROWS_Q;
    float2 mls[NSPLIT];
    #pragma unroll
    for (int s = 0; s < NSPLIT; ++s)
        mls[s] = ml[((size_t)(s * BATCH + b) * NH + h) * ROWS_Q + q];
    float M = fmaxf(fmaxf(mls[0].x, mls[1].x), fmaxf(mls[2].x, mls[3].x));
    float w[NSPLIT], wt = 0.0f;
    #pragma unroll
    for (int s = 0; s < NSPLIT; ++s) {
        w[s] = mls[s].y * __expf(mls[s].x - M);
        wt += w[s];
    }
    float winv = 1.0f / wt;
    size_t off = (size_t)row * 512 + g * 8;
    const bf16* op[NSPLIT] = {o0, o1, o2, o3};
    float acc[8] = {};
    #pragma unroll
    for (int s = 0; s < NSPLIT; ++s) {
        bf16x8 v = *(const bf16x8*)(op[s] + off);
        float ws = w[s] * winv;
        #pragma unroll
        for (int e = 0; e < 8; ++e) acc[e] += ws * (float)v[e];
    }
    bf16x8 r;
    #pragma unroll
    for (int e = 0; e < 8; ++e) r[e] = (bf16)acc[e];
    *(bf16x8*)(outb + off) = r;
}

extern "C" void kernel_launch(void* const* d_in, const int* in_sizes, int n_in,
                              void* d_out, int out_size, void* d_ws, size_t ws_size,
                              hipStream_t stream)
{
    const float* x     = (const float*)d_in[0];
    const float* slow  = (const float*)d_in[1];
    const float* Wq_in = (const float*)d_in[3];
    const float* bq_in = (const float*)d_in[4];
    const float* Wm    = (const float*)d_in[5];
    const float* bm    = (const float*)d_in[6];
    const float* Wq    = (const float*)d_in[7];
    const float* bq    = (const float*)d_in[8];
    const float* Wk    = (const float*)d_in[9];
    const float* bk    = (const float*)d_in[10];
    const float* Wv    = (const float*)d_in[11];
    const float* bv    = (const float*)d_in[12];
    const float* Wo    = (const float*)d_in[13];
    const float* bo    = (const float*)d_in[14];
    const float* g1    = (const float*)d_in[15];
    const float* be1   = (const float*)d_in[16];
    const float* W1    = (const float*)d_in[17];
    const float* b1    = (const float*)d_in[18];
    const float* W2    = (const float*)d_in[19];
    const float* b2    = (const float*)d_in[20];
    const float* g2    = (const float*)d_in[21];
    const float* be2   = (const float*)d_in[22];
    const float* M1    = (const float*)d_in[23];
    const float* bm1   = (const float*)d_in[24];
    const float* M2    = (const float*)d_in[25];
    const float* bm2   = (const float*)d_in[26];
    float* out = (float*)d_out;

    // ---- workspace layout ----
    float* q_in_f = (float*)d_ws;                         // MQ*512 f32
    float* ob     = q_in_f + (size_t)MQ * HID;            // MQ*512 f32
    float* bkv    = ob + (size_t)MQ * HID;                // 1024 f32
    bf16* shared_b = (bf16*)(bkv + 1024);                 // MQ*1024
    bf16* q_in_b = shared_b + (size_t)MQ * FF;            // MQ*512
    bf16* kv_b   = q_in_b + (size_t)MQ * HID;             // MK*1024
    bf16* h_b    = kv_b + (size_t)MK * EMB;               // MQ*512
    bf16* q16    = h_b + (size_t)MQ * HID;                // MQ*512
    bf16* kv16   = q16 + (size_t)MQ * HID;                // MK*1024 (k|v fused)
    bf16* qbt    = kv16 + (size_t)MK * EMB;               // MQ*512
    bf16* kbt    = qbt + (size_t)MQ * HID;                // MK*512
    bf16* Vt     = kbt + (size_t)MK * HID;                // 8*128*2048
    bf16* Wq_in_t = Vt + (size_t)8 * HD * ROWS_K;         // 512*896
    bf16* Wq_t  = Wq_in_t + 512 * 896;                    // 512*512
    bf16* kvw_t = Wq_t + 512 * 512;                       // 1024*1024 (Wk_t | Wv_t)
    bf16* Wo_t  = kvw_t + 1024 * 1024;                    // 512*512
    bf16* W1_t  = Wo_t + 512 * 512;                       // 1024*512
    bf16* W2_t  = W1_t + 1024 * 512;                      // 512*1024
    bf16* M1_t  = W2_t + 512 * 1024;                      // 1024*512
    bf16* M2_t  = M1_t + 1024 * 512;                      // 896*1024
    float2* mlbuf = (float2*)(M2_t + 896 * 1024);         // 4*2*4*6272 float2
    bf16* slow_b = shared_b;
    bf16* attn_b = shared_b;
    bf16* ff1_b  = shared_b;
    bf16* m1_b   = shared_b;
    // split-KV partial-O buffers alias buffers dead during attention:
    bf16* op0 = shared_b;                      // slow_b dead after q_in GEMM
    bf16* op1 = shared_b + (size_t)MQ * HID;   // second half of shared_b
    bf16* op2 = q16;                           // dead after rope
    bf16* op3 = q_in_b;                        // dead after q projection

    dim3 blk(256);

    // ---- all weight transposes in one launch ----
    TDescs td;
    int t0 = 0;
    auto set = [&](int i, const float* s, bf16* d, int K, int N) {
        td.d[i] = {s, d, K, N, t0};
        t0 += (N / 32) * (K / 32);
    };
    set(0, Wq_in, Wq_in_t, 896, 512);
    set(1, Wq,    Wq_t,    512, 512);
    set(2, Wk,    kvw_t,              1024, 512);
    set(3, Wv,    kvw_t + 512 * 1024, 1024, 512);
    set(4, Wo,    Wo_t,    512, 512);
    set(5, W1,    W1_t,    512, 1024);
    set(6, W2,    W2_t,    1024, 512);
    set(7, M1,    M1_t,    512, 1024);
    set(8, M2,    M2_t,    1024, 896);
    transpose_all<<<t0, blk, 0, stream>>>(td);

    hipMemcpyAsync(bkv,       bk, 512 * sizeof(float), hipMemcpyDeviceToDevice, stream);
    hipMemcpyAsync(bkv + 512, bv, 512 * sizeof(float), hipMemcpyDeviceToDevice, stream);

    cvt_kernel<<<(MQ * DQ / 4 + 255) / 256, blk, 0, stream>>>(slow, slow_b, MQ * DQ / 4);
    kv_kernel<<<(MK * EMB) / 256, blk, 0, stream>>>(x, Wm, bm, kv_b);

    // q_in = slow @ Wq_in + bq_in -> fp32 (residual) + bf16
    mgemm64<OP_BIAS, true, true><<<dim3(4, 196), blk, 0, stream>>>(
        slow_b, Wq_in_t, bq_in, nullptr, q_in_f, q_in_b, MQ, HID, DQ);
    // q projection -> bf16
    mgemm64<OP_BIAS, false, true><<<dim3(4, 196), blk, 0, stream>>>(
        q_in_b, Wq_t, bq, nullptr, nullptr, q16, MQ, HID, HID);
    // fused k|v projection -> kv16 (MK x 1024)
    mgemm64<OP_BIAS, false, true><<<dim3(8, 64), blk, 0, stream>>>(
        kv_b, kvw_t, bkv, nullptr, nullptr, kv16, MK, 1024, EMB);
    // fused RoPE (q scaled by 1/sqrt(128); k from kv16)
    rope2_kernel<<<((MQ + MK) * 128 + 255) / 256, blk, 0, stream>>>(q16, kv16, qbt, kbt);
    // V transpose
    vt_tiled<<<dim3(32, 2, 8), blk, 0, stream>>>(kv16, Vt);
    // split-KV MFMA flash attention: 392 x 4 = 1568 blocks
    mattn_kernel<<<dim3(392, NSPLIT), blk, 0, stream>>>(
        qbt, kbt, Vt, op0, op1, op2, op3, mlbuf);
    // combine partials -> attn_b (aliases op0; per-thread read-before-write)
    combine_kernel<<<(MQ * 64 + 255) / 256, blk, 0, stream>>>(
        op0, op1, op2, op3, mlbuf, attn_b);
    // pre_ln = attn @ Wo + bo + q_in
    mgemm64<OP_RES, true, false><<<dim3(4, 196), blk, 0, stream>>>(
        attn_b, Wo_t, bo, q_in_f, ob, nullptr, MQ, HID, HID);
    ln_kernel<<<MQ / 4, blk, 0, stream>>>(ob, g1, be1, h_b);
    mgemm<OP_GELU, false, true><<<dim3(8, 98), blk, 0, stream>>>(
        h_b, W1_t, b1, nullptr, nullptr, ff1_b, MQ, FF, HID);
    mgemm64<OP_RES, true, false><<<dim3(4, 196), blk, 0, stream>>>(
        ff1_b, W2_t, b2, ob, q_in_f, nullptr, MQ, HID, FF);
    ln_kernel<<<MQ / 4, blk, 0, stream>>>(q_in_f, g2, be2, h_b);
    mgemm<OP_GELU, false, true><<<dim3(8, 98), blk, 0, stream>>>(
        h_b, M1_t, bm1, nullptr, nullptr, m1_b, MQ, 2 * HID, HID);
    mgemm<OP_BIAS, true, false><<<dim3(7, 98), blk, 0, stream>>>(
        m1_b, M2_t, bm2, nullptr, out, nullptr, MQ, OUTD, 2 * HID);
}